// Round 2
// baseline (28462.390 us; speedup 1.0000x reference)
//
#include <hip/hip_runtime.h>

// GRU: S=512, B=64, I=H=1024, L=3. fp32 in/out.
// fp16 MFMA with Markidis 3-product split (hi/lo) => fp32-accurate GEMMs.
// Layer l>0 input is its own hidden state (faithful to reference).

typedef _Float16 f16x8 __attribute__((ext_vector_type(8)));
typedef _Float16 f16x4 __attribute__((ext_vector_type(4)));
typedef float    f32x4 __attribute__((ext_vector_type(4)));

#define HD    1024
#define NB    64
#define NSTEP 512
#define LBH   (3*NB*HD)   // 196608

#define MFMA(acc, a, b) acc = __builtin_amdgcn_mfma_f32_16x16x32_f16(a, b, acc, 0, 0, 0)

// ---------------- prep kernels ----------------
__global__ void split_kernel4(const float4* __restrict__ src, f16x4* __restrict__ dh,
                              f16x4* __restrict__ dl, int n4) {
    int i = blockIdx.x * blockDim.x + threadIdx.x, s = gridDim.x * blockDim.x;
    for (; i < n4; i += s) {
        float4 v = src[i];
        _Float16 a = (_Float16)v.x, b = (_Float16)v.y, c = (_Float16)v.z, d = (_Float16)v.w;
        f16x4 hh = {a, b, c, d};
        f16x4 ll = {(_Float16)(v.x - (float)a), (_Float16)(v.y - (float)b),
                    (_Float16)(v.z - (float)c), (_Float16)(v.w - (float)d)};
        dh[i] = hh; dl[i] = ll;
    }
}

__global__ void sumsplit_kernel4(const float4* __restrict__ sa, const float4* __restrict__ sb,
                                 f16x4* __restrict__ dh, f16x4* __restrict__ dl, int n4) {
    int i = blockIdx.x * blockDim.x + threadIdx.x, s = gridDim.x * blockDim.x;
    for (; i < n4; i += s) {
        float4 va = sa[i], vb = sb[i];
        float x = va.x + vb.x, y = va.y + vb.y, z = va.z + vb.z, w = va.w + vb.w;
        _Float16 a = (_Float16)x, b = (_Float16)y, c = (_Float16)z, d = (_Float16)w;
        f16x4 hh = {a, b, c, d};
        f16x4 ll = {(_Float16)(x - (float)a), (_Float16)(y - (float)b),
                    (_Float16)(z - (float)c), (_Float16)(w - (float)d)};
        dh[i] = hh; dl[i] = ll;
    }
}

__global__ void bias_kernel(const float* __restrict__ a, const float* __restrict__ b,
                            float* __restrict__ d, int n) {
    int i = blockIdx.x * blockDim.x + threadIdx.x;
    if (i < n) d[i] = a[i] + b[i];
}

__global__ void hinit_kernel(const float4* __restrict__ h0, float4* __restrict__ h32,
                             f16x4* __restrict__ hh, f16x4* __restrict__ hl, int n4) {
    int i = blockIdx.x * blockDim.x + threadIdx.x, s = gridDim.x * blockDim.x;
    for (; i < n4; i += s) {
        float4 v = h0[i];
        h32[i] = v;
        _Float16 a = (_Float16)v.x, b = (_Float16)v.y, c = (_Float16)v.z, d = (_Float16)v.w;
        f16x4 hv = {a, b, c, d};
        f16x4 lv = {(_Float16)(v.x - (float)a), (_Float16)(v.y - (float)b),
                    (_Float16)(v.z - (float)c), (_Float16)(v.w - (float)d)};
        hh[i] = hv; hl[i] = lv;
    }
}

// ---------------- step kernel ----------------
// grid = 384 x 64 threads. u: layer = u>>7, mh = (u&127)>>6 (batch half), jt = u&63.
// Wave computes h'[layer][mh*32 .. mh*32+31][jt*16 .. jt*16+15].
// W0  (6144,1024):  rows [0,3072)=Wih gates r,z,n ; [3072,6144)=Whh gates r,z,n   (layer 0)
// W12 (2,4096,1024): rows [0,2048)=Wih_rz+Whh_rz ; [2048,3072)=Wih_n ; [3072,4096)=Whh_n
__global__ __launch_bounds__(64) void gru_step(
    const _Float16* __restrict__ xh, const _Float16* __restrict__ xl,   // (64,1024) at t
    const _Float16* __restrict__ hh, const _Float16* __restrict__ hl,   // (3,64,1024)
    const float*    __restrict__ h32s,
    _Float16* __restrict__ hhd, _Float16* __restrict__ hld,
    float*    __restrict__ h32d,
    const _Float16* __restrict__ W0h,  const _Float16* __restrict__ W0l,
    const _Float16* __restrict__ W12h, const _Float16* __restrict__ W12l,
    const float*    __restrict__ bsum)
{
    const int lane = threadIdx.x;
    const int lr = lane & 15, hi4 = lane >> 4;
    const int u = blockIdx.x;
    const int layer = u >> 7;
    const int mh = (u & 127) >> 6;
    const int jt = u & 63;
    const int j = jt * 16 + lr;
    const float* bs = bsum + layer * 3072;
    const int aoff = (mh * 32 + lr) * 128 + hi4;   // f16x8 index; +2048 => +16 rows
    const int boff = j * 128 + hi4;

    if (layer == 0) {
        f32x4 ai[2][3], ah[2][3];
#pragma unroll
        for (int mi = 0; mi < 2; ++mi)
#pragma unroll
            for (int g = 0; g < 3; ++g) { ai[mi][g] = {0,0,0,0}; ah[mi][g] = {0,0,0,0}; }
        const f16x8* pxh = (const f16x8*)xh + aoff;
        const f16x8* pxl = (const f16x8*)xl + aoff;
        const f16x8* phh = (const f16x8*)hh + aoff;
        const f16x8* phl = (const f16x8*)hl + aoff;
        const f16x8* bIh = (const f16x8*)W0h + boff;
        const f16x8* bIl = (const f16x8*)W0l + boff;
        const f16x8* bHh = bIh + 393216;   // +3072 rows
        const f16x8* bHl = bIl + 393216;
        for (int w = 0; w < 128; w += 4) {
            f16x8 aXh0 = pxh[w], aXh1 = pxh[w + 2048];
            f16x8 aXl0 = pxl[w], aXl1 = pxl[w + 2048];
            f16x8 aHh0 = phh[w], aHh1 = phh[w + 2048];
            f16x8 aHl0 = phl[w], aHl1 = phl[w + 2048];
#pragma unroll
            for (int g = 0; g < 3; ++g) {
                f16x8 wIh = bIh[g * 131072 + w], wIl = bIl[g * 131072 + w];
                f16x8 wHh = bHh[g * 131072 + w], wHl = bHl[g * 131072 + w];
                MFMA(ai[0][g], aXh0, wIh); MFMA(ai[1][g], aXh1, wIh);
                MFMA(ai[0][g], aXl0, wIh); MFMA(ai[1][g], aXl1, wIh);
                MFMA(ai[0][g], aXh0, wIl); MFMA(ai[1][g], aXh1, wIl);
                MFMA(ah[0][g], aHh0, wHh); MFMA(ah[1][g], aHh1, wHh);
                MFMA(ah[0][g], aHl0, wHh); MFMA(ah[1][g], aHl1, wHh);
                MFMA(ah[0][g], aHh0, wHl); MFMA(ah[1][g], aHh1, wHl);
            }
        }
#pragma unroll
        for (int mi = 0; mi < 2; ++mi)
#pragma unroll
            for (int e = 0; e < 4; ++e) {
                int b = mh * 32 + mi * 16 + hi4 * 4 + e;
                int idx = b * HD + j;
                float rr = ai[mi][0][e] + ah[mi][0][e] + bs[j];
                float zz = ai[mi][1][e] + ah[mi][1][e] + bs[1024 + j];
                float r = 1.f / (1.f + expf(-rr));
                float z = 1.f / (1.f + expf(-zz));
                float n = tanhf(ai[mi][2][e] + bs[2048 + j] + r * ah[mi][2][e]);
                float hp = h32s[idx];
                float hn = n + z * (hp - n);
                h32d[idx] = hn;
                _Float16 hv = (_Float16)hn;
                hhd[idx] = hv;
                hld[idx] = (_Float16)(hn - (float)hv);
            }
    } else {
        f32x4 ac[2][4];
#pragma unroll
        for (int mi = 0; mi < 2; ++mi)
#pragma unroll
            for (int g = 0; g < 4; ++g) ac[mi][g] = {0,0,0,0};
        const f16x8* phh = (const f16x8*)(hh + layer * 65536) + aoff;
        const f16x8* phl = (const f16x8*)(hl + layer * 65536) + aoff;
        const f16x8* bh = (const f16x8*)(W12h + (size_t)(layer - 1) * 4096 * 1024) + boff;
        const f16x8* bl = (const f16x8*)(W12l + (size_t)(layer - 1) * 4096 * 1024) + boff;
        for (int w = 0; w < 128; w += 4) {
            f16x8 aH0 = phh[w], aH1 = phh[w + 2048];
            f16x8 aL0 = phl[w], aL1 = phl[w + 2048];
#pragma unroll
            for (int g = 0; g < 4; ++g) {
                f16x8 wgh = bh[g * 131072 + w], wgl = bl[g * 131072 + w];
                MFMA(ac[0][g], aH0, wgh); MFMA(ac[1][g], aH1, wgh);
                MFMA(ac[0][g], aL0, wgh); MFMA(ac[1][g], aL1, wgh);
                MFMA(ac[0][g], aH0, wgl); MFMA(ac[1][g], aH1, wgl);
            }
        }
#pragma unroll
        for (int mi = 0; mi < 2; ++mi)
#pragma unroll
            for (int e = 0; e < 4; ++e) {
                int b = mh * 32 + mi * 16 + hi4 * 4 + e;
                int idx = layer * 65536 + b * HD + j;
                float r = 1.f / (1.f + expf(-(ac[mi][0][e] + bs[j])));
                float z = 1.f / (1.f + expf(-(ac[mi][1][e] + bs[1024 + j])));
                float n = tanhf(ac[mi][2][e] + bs[2048 + j] + r * ac[mi][3][e]);
                float hp = h32s[idx];
                float hn = n + z * (hp - n);
                h32d[idx] = hn;
                _Float16 hv = (_Float16)hn;
                hhd[idx] = hv;
                hld[idx] = (_Float16)(hn - (float)hv);
            }
    }
}

// ---------------- launch ----------------
extern "C" void kernel_launch(void* const* d_in, const int* in_sizes, int n_in,
                              void* d_out, int out_size, void* d_ws, size_t ws_size,
                              hipStream_t stream) {
    (void)in_sizes; (void)n_in; (void)out_size; (void)ws_size;
    const float* x   = (const float*)d_in[0];   // (512,64,1024)
    const float* h0  = (const float*)d_in[1];   // (3,64,1024)
    const float* Wih = (const float*)d_in[2];   // (3,3072,1024)
    const float* Whh = (const float*)d_in[3];   // (3,3072,1024)
    const float* bih = (const float*)d_in[4];   // (3,3072)
    const float* bhh = (const float*)d_in[5];   // (3,3072)

    char* ws = (char*)d_ws;
    _Float16* xh   = (_Float16*)(ws + 0);            //  67,108,864
    _Float16* xl   = (_Float16*)(ws + 67108864);     //  67,108,864
    _Float16* W0h  = (_Float16*)(ws + 134217728);    //  12,582,912
    _Float16* W0l  = (_Float16*)(ws + 146800640);    //  12,582,912
    _Float16* W12h = (_Float16*)(ws + 159383552);    //  16,777,216
    _Float16* W12l = (_Float16*)(ws + 176160768);    //  16,777,216
    float*    bsum = (float*)   (ws + 192937984);    //      36,864
    float*    h32  = (float*)   (ws + 192974848);    //   1,572,864 (2 slots)
    _Float16* hhb  = (_Float16*)(ws + 194547712);    //     786,432 (2 slots)
    _Float16* hlb  = (_Float16*)(ws + 195334144);    //     786,432 (2 slots)
    // total ~196.1 MB

    const int thr = 256;
    const int LW = 3072 * 1024;   // per-layer weight stride in inputs

    // x split: 33,554,432 elems
    split_kernel4<<<4096, thr, 0, stream>>>((const float4*)x, (f16x4*)xh, (f16x4*)xl, 8388608);
    // layer-0 weights -> W0 rows [0,3072)=Wih, [3072,6144)=Whh
    split_kernel4<<<3072, thr, 0, stream>>>((const float4*)Wih, (f16x4*)W0h, (f16x4*)W0l, 786432);
    split_kernel4<<<3072, thr, 0, stream>>>((const float4*)Whh,
                                            (f16x4*)(W0h + 3072 * 1024), (f16x4*)(W0l + 3072 * 1024), 786432);
    // layers 1,2 -> W12: rows [0,2048)=Wih_rz+Whh_rz, [2048,3072)=Wih_n, [3072,4096)=Whh_n
    for (int l = 1; l <= 2; ++l) {
        size_t dst = (size_t)(l - 1) * 4096 * 1024;
        sumsplit_kernel4<<<2048, thr, 0, stream>>>((const float4*)(Wih + (size_t)l * LW),
                                                   (const float4*)(Whh + (size_t)l * LW),
                                                   (f16x4*)(W12h + dst), (f16x4*)(W12l + dst),
                                                   2048 * 1024 / 4);
        split_kernel4<<<1024, thr, 0, stream>>>((const float4*)(Wih + (size_t)l * LW + 2048 * 1024),
                                                (f16x4*)(W12h + dst + 2048 * 1024),
                                                (f16x4*)(W12l + dst + 2048 * 1024), 262144);
        split_kernel4<<<1024, thr, 0, stream>>>((const float4*)(Whh + (size_t)l * LW + 2048 * 1024),
                                                (f16x4*)(W12h + dst + 3072 * 1024),
                                                (f16x4*)(W12l + dst + 3072 * 1024), 262144);
    }
    bias_kernel<<<36, thr, 0, stream>>>(bih, bhh, bsum, 9216);
    hinit_kernel<<<192, thr, 0, stream>>>((const float4*)h0, (float4*)h32,
                                          (f16x4*)hhb, (f16x4*)hlb, LBH / 4);

    // 512 sequential steps; ping-pong h slots; last step writes fp32 h to d_out
    for (int t = 0; t < NSTEP; ++t) {
        int s0 = t & 1, s1 = (t + 1) & 1;
        float* h32d = (t == NSTEP - 1) ? (float*)d_out : h32 + s1 * LBH;
        gru_step<<<384, 64, 0, stream>>>(xh + (size_t)t * NB * HD, xl + (size_t)t * NB * HD,
                                         hhb + s0 * LBH, hlb + s0 * LBH, h32 + s0 * LBH,
                                         hhb + s1 * LBH, hlb + s1 * LBH, h32d,
                                         W0h, W0l, W12h, W12l, bsum);
    }
}

// Round 3
// 13100.792 us; speedup vs baseline: 2.1726x; 2.1726x over previous
//
#include <hip/hip_runtime.h>

// GRU: S=512, B=64, I=H=1024, L=3. fp32 in/out.
// fp16 MFMA with Markidis 3-product split (hi/lo) => fp32-accurate GEMMs.
// Step kernel v3: 256 blocks (1/CU) x 256 threads (4 waves, K-split 4),
// LDS cross-wave reduce, fused gate epilogue, XCD-stable tile map.

typedef _Float16 f16x8 __attribute__((ext_vector_type(8)));
typedef _Float16 f16x4 __attribute__((ext_vector_type(4)));
typedef float    f32x4 __attribute__((ext_vector_type(4)));

#define HD    1024
#define NB    64
#define NSTEP 512
#define LBH   (3*NB*HD)   // 196608

#define MFMA(acc, a, b) acc = __builtin_amdgcn_mfma_f32_16x16x32_f16(a, b, acc, 0, 0, 0)

// ---------------- prep kernels ----------------
__global__ void split_kernel4(const float4* __restrict__ src, f16x4* __restrict__ dh,
                              f16x4* __restrict__ dl, int n4) {
    int i = blockIdx.x * blockDim.x + threadIdx.x, s = gridDim.x * blockDim.x;
    for (; i < n4; i += s) {
        float4 v = src[i];
        _Float16 a = (_Float16)v.x, b = (_Float16)v.y, c = (_Float16)v.z, d = (_Float16)v.w;
        f16x4 hh = {a, b, c, d};
        f16x4 ll = {(_Float16)(v.x - (float)a), (_Float16)(v.y - (float)b),
                    (_Float16)(v.z - (float)c), (_Float16)(v.w - (float)d)};
        dh[i] = hh; dl[i] = ll;
    }
}

__global__ void sumsplit_kernel4(const float4* __restrict__ sa, const float4* __restrict__ sb,
                                 f16x4* __restrict__ dh, f16x4* __restrict__ dl, int n4) {
    int i = blockIdx.x * blockDim.x + threadIdx.x, s = gridDim.x * blockDim.x;
    for (; i < n4; i += s) {
        float4 va = sa[i], vb = sb[i];
        float x = va.x + vb.x, y = va.y + vb.y, z = va.z + vb.z, w = va.w + vb.w;
        _Float16 a = (_Float16)x, b = (_Float16)y, c = (_Float16)z, d = (_Float16)w;
        f16x4 hh = {a, b, c, d};
        f16x4 ll = {(_Float16)(x - (float)a), (_Float16)(y - (float)b),
                    (_Float16)(z - (float)c), (_Float16)(w - (float)d)};
        dh[i] = hh; dl[i] = ll;
    }
}

__global__ void bias_kernel(const float* __restrict__ a, const float* __restrict__ b,
                            float* __restrict__ d, int n) {
    int i = blockIdx.x * blockDim.x + threadIdx.x;
    if (i < n) d[i] = a[i] + b[i];
}

__global__ void hinit_kernel(const float4* __restrict__ h0, float4* __restrict__ h32,
                             f16x4* __restrict__ hh, f16x4* __restrict__ hl, int n4) {
    int i = blockIdx.x * blockDim.x + threadIdx.x, s = gridDim.x * blockDim.x;
    for (; i < n4; i += s) {
        float4 v = h0[i];
        h32[i] = v;
        _Float16 a = (_Float16)v.x, b = (_Float16)v.y, c = (_Float16)v.z, d = (_Float16)v.w;
        f16x4 hv = {a, b, c, d};
        f16x4 lv = {(_Float16)(v.x - (float)a), (_Float16)(v.y - (float)b),
                    (_Float16)(v.z - (float)c), (_Float16)(v.w - (float)d)};
        hh[i] = hv; hl[i] = lv;
    }
}

// ---------------- step kernel ----------------
// 256 blocks x 256 threads (4 waves). Tile map (XCD-stable):
//   tile = (bid&7)*32 + (bid>>3)
//   tile in [0,128):   layer 0, jt = tile>>1, mh = tile&1  (32 batch rows)
//   tile in [128,192): layer 1, jt = tile-128              (64 batch rows)
//   tile in [192,256): layer 2, jt = tile-192
// Wave w handles K-chunk [w*256,(w+1)*256); fp32 reduce via LDS; fused epilogue.
// W0  (6144,1024): rows [0,3072)=Wih r,z,n ; [3072,6144)=Whh r,z,n     (layer 0)
// W12 (2,4096,1024): [0,1024)=c_r ; [1024,2048)=c_z ; [2048,3072)=Win ; [3072,4096)=Whn
__global__ __launch_bounds__(256, 1) void gru_step(
    const _Float16* __restrict__ xh, const _Float16* __restrict__ xl,   // (64,1024) at t
    const _Float16* __restrict__ hhp, const _Float16* __restrict__ hlp, // (3,64,1024)
    const float*    __restrict__ h32s,
    _Float16* __restrict__ hhd, _Float16* __restrict__ hld,
    float*    __restrict__ h32d,
    const _Float16* __restrict__ W0h,  const _Float16* __restrict__ W0l,
    const _Float16* __restrict__ W12h, const _Float16* __restrict__ W12l,
    const float*    __restrict__ bsum)
{
    __shared__ f32x4 red[4][16][64];

    const int lane = threadIdx.x & 63;
    const int wv   = threadIdx.x >> 6;
    const int lr = lane & 15, hi4 = lane >> 4;
    const int bid = blockIdx.x;
    const int tile = (bid & 7) * 32 + (bid >> 3);

    const int kb0 = wv * 32 + hi4;   // f16x8 index base within a 1024-K row

    if (tile < 128) {
        // ---------------- layer 0, 32 batch rows ----------------
        const int jt = tile >> 1, mh = tile & 1;
        const int j = jt * 16 + lr;
        const float* bs = bsum;
        const int row0 = mh * 32 + lr;

        const f16x8* pxh = (const f16x8*)xh;
        const f16x8* pxl = (const f16x8*)xl;
        const f16x8* phh = (const f16x8*)hhp;   // layer 0 base
        const f16x8* phl = (const f16x8*)hlp;

        const f16x8* wRih_h = (const f16x8*)W0h + j * 128 + kb0;
        const f16x8* wRih_l = (const f16x8*)W0l + j * 128 + kb0;
        // z: +131072, n: +262144, Whh base: +393216 (f16x8 units)

        f32x4 r0{0,0,0,0}, r1{0,0,0,0}, z0{0,0,0,0}, z1{0,0,0,0};
        f32x4 ni0{0,0,0,0}, ni1{0,0,0,0}, nh0{0,0,0,0}, nh1{0,0,0,0};

        const int a0 = row0 * 128 + kb0, a1 = (row0 + 16) * 128 + kb0;
#pragma unroll
        for (int it = 0; it < 8; ++it) {
            const int ka = it * 4;
            f16x8 axh0 = pxh[a0 + ka], axh1 = pxh[a1 + ka];
            f16x8 axl0 = pxl[a0 + ka], axl1 = pxl[a1 + ka];
            f16x8 ahh0 = phh[a0 + ka], ahh1 = phh[a1 + ka];
            f16x8 ahl0 = phl[a0 + ka], ahl1 = phl[a1 + ka];
            f16x8 wa, wb;
            // gate r
            wa = wRih_h[ka]; wb = wRih_l[ka];
            MFMA(r0, axh0, wa); MFMA(r1, axh1, wa);
            MFMA(r0, axl0, wa); MFMA(r1, axl1, wa);
            MFMA(r0, axh0, wb); MFMA(r1, axh1, wb);
            wa = wRih_h[393216 + ka]; wb = wRih_l[393216 + ka];
            MFMA(r0, ahh0, wa); MFMA(r1, ahh1, wa);
            MFMA(r0, ahl0, wa); MFMA(r1, ahl1, wa);
            MFMA(r0, ahh0, wb); MFMA(r1, ahh1, wb);
            // gate z
            wa = wRih_h[131072 + ka]; wb = wRih_l[131072 + ka];
            MFMA(z0, axh0, wa); MFMA(z1, axh1, wa);
            MFMA(z0, axl0, wa); MFMA(z1, axl1, wa);
            MFMA(z0, axh0, wb); MFMA(z1, axh1, wb);
            wa = wRih_h[524288 + ka]; wb = wRih_l[524288 + ka];
            MFMA(z0, ahh0, wa); MFMA(z1, ahh1, wa);
            MFMA(z0, ahl0, wa); MFMA(z1, ahl1, wa);
            MFMA(z0, ahh0, wb); MFMA(z1, ahh1, wb);
            // gate n, input part
            wa = wRih_h[262144 + ka]; wb = wRih_l[262144 + ka];
            MFMA(ni0, axh0, wa); MFMA(ni1, axh1, wa);
            MFMA(ni0, axl0, wa); MFMA(ni1, axl1, wa);
            MFMA(ni0, axh0, wb); MFMA(ni1, axh1, wb);
            // gate n, hidden part
            wa = wRih_h[655360 + ka]; wb = wRih_l[655360 + ka];
            MFMA(nh0, ahh0, wa); MFMA(nh1, ahh1, wa);
            MFMA(nh0, ahl0, wa); MFMA(nh1, ahl1, wa);
            MFMA(nh0, ahh0, wb); MFMA(nh1, ahh1, wb);
        }
        red[wv][0][lane] = r0;  red[wv][1][lane] = r1;
        red[wv][2][lane] = z0;  red[wv][3][lane] = z1;
        red[wv][4][lane] = ni0; red[wv][5][lane] = ni1;
        red[wv][6][lane] = nh0; red[wv][7][lane] = nh1;
        __syncthreads();
        if (wv < 2) {
            f32x4 R  = red[0][0 + wv][lane] + red[1][0 + wv][lane] + red[2][0 + wv][lane] + red[3][0 + wv][lane];
            f32x4 Z  = red[0][2 + wv][lane] + red[1][2 + wv][lane] + red[2][2 + wv][lane] + red[3][2 + wv][lane];
            f32x4 NI = red[0][4 + wv][lane] + red[1][4 + wv][lane] + red[2][4 + wv][lane] + red[3][4 + wv][lane];
            f32x4 NH = red[0][6 + wv][lane] + red[1][6 + wv][lane] + red[2][6 + wv][lane] + red[3][6 + wv][lane];
#pragma unroll
            for (int e = 0; e < 4; ++e) {
                int b = mh * 32 + wv * 16 + hi4 * 4 + e;
                int idx = b * HD + j;
                float r = 1.f / (1.f + expf(-(R[e] + bs[j])));
                float z = 1.f / (1.f + expf(-(Z[e] + bs[1024 + j])));
                float n = tanhf(NI[e] + bs[2048 + j] + r * NH[e]);
                float hp = h32s[idx];
                float hn = n + z * (hp - n);
                h32d[idx] = hn;
                _Float16 hv = (_Float16)hn;
                hhd[idx] = hv;
                hld[idx] = (_Float16)(hn - (float)hv);
            }
        }
    } else {
        // ---------------- layers 1,2, full 64-row batch ----------------
        const int layer = (tile < 192) ? 1 : 2;
        const int jt = tile - (layer == 1 ? 128 : 192);
        const int j = jt * 16 + lr;
        const float* bs = bsum + layer * 3072;

        const f16x8* phh = (const f16x8*)hhp + layer * 8192;
        const f16x8* phl = (const f16x8*)hlp + layer * 8192;
        const f16x8* wh = (const f16x8*)W12h + (size_t)(layer - 1) * 524288 + j * 128 + kb0;
        const f16x8* wl = (const f16x8*)W12l + (size_t)(layer - 1) * 524288 + j * 128 + kb0;
        // c_z: +131072, Win: +262144, Whn: +393216 (f16x8 units)

        f32x4 r[4], z[4], ni[4], nh[4];
#pragma unroll
        for (int m = 0; m < 4; ++m) { r[m] = {0,0,0,0}; z[m] = {0,0,0,0}; ni[m] = {0,0,0,0}; nh[m] = {0,0,0,0}; }

#pragma unroll
        for (int it = 0; it < 8; ++it) {
            const int ka = it * 4;
            f16x8 ah[4], al[4];
#pragma unroll
            for (int m = 0; m < 4; ++m) {
                ah[m] = phh[(m * 16 + lr) * 128 + kb0 + ka];
                al[m] = phl[(m * 16 + lr) * 128 + kb0 + ka];
            }
            f16x8 wa, wb;
            wa = wh[ka]; wb = wl[ka];
#pragma unroll
            for (int m = 0; m < 4; ++m) { MFMA(r[m], ah[m], wa); MFMA(r[m], al[m], wa); MFMA(r[m], ah[m], wb); }
            wa = wh[131072 + ka]; wb = wl[131072 + ka];
#pragma unroll
            for (int m = 0; m < 4; ++m) { MFMA(z[m], ah[m], wa); MFMA(z[m], al[m], wa); MFMA(z[m], ah[m], wb); }
            wa = wh[262144 + ka]; wb = wl[262144 + ka];
#pragma unroll
            for (int m = 0; m < 4; ++m) { MFMA(ni[m], ah[m], wa); MFMA(ni[m], al[m], wa); MFMA(ni[m], ah[m], wb); }
            wa = wh[393216 + ka]; wb = wl[393216 + ka];
#pragma unroll
            for (int m = 0; m < 4; ++m) { MFMA(nh[m], ah[m], wa); MFMA(nh[m], al[m], wa); MFMA(nh[m], ah[m], wb); }
        }
#pragma unroll
        for (int m = 0; m < 4; ++m) {
            red[wv][0 + m][lane]  = r[m];
            red[wv][4 + m][lane]  = z[m];
            red[wv][8 + m][lane]  = ni[m];
            red[wv][12 + m][lane] = nh[m];
        }
        __syncthreads();
        {
            f32x4 R  = red[0][0 + wv][lane]  + red[1][0 + wv][lane]  + red[2][0 + wv][lane]  + red[3][0 + wv][lane];
            f32x4 Z  = red[0][4 + wv][lane]  + red[1][4 + wv][lane]  + red[2][4 + wv][lane]  + red[3][4 + wv][lane];
            f32x4 NI = red[0][8 + wv][lane]  + red[1][8 + wv][lane]  + red[2][8 + wv][lane]  + red[3][8 + wv][lane];
            f32x4 NH = red[0][12 + wv][lane] + red[1][12 + wv][lane] + red[2][12 + wv][lane] + red[3][12 + wv][lane];
#pragma unroll
            for (int e = 0; e < 4; ++e) {
                int b = wv * 16 + hi4 * 4 + e;
                int idx = layer * 65536 + b * HD + j;
                float rr = 1.f / (1.f + expf(-(R[e] + bs[j])));
                float zz = 1.f / (1.f + expf(-(Z[e] + bs[1024 + j])));
                float n = tanhf(NI[e] + bs[2048 + j] + rr * NH[e]);
                float hp = h32s[idx];
                float hn = n + zz * (hp - n);
                h32d[idx] = hn;
                _Float16 hv = (_Float16)hn;
                hhd[idx] = hv;
                hld[idx] = (_Float16)(hn - (float)hv);
            }
        }
    }
}

// ---------------- launch ----------------
extern "C" void kernel_launch(void* const* d_in, const int* in_sizes, int n_in,
                              void* d_out, int out_size, void* d_ws, size_t ws_size,
                              hipStream_t stream) {
    (void)in_sizes; (void)n_in; (void)out_size; (void)ws_size;
    const float* x   = (const float*)d_in[0];   // (512,64,1024)
    const float* h0  = (const float*)d_in[1];   // (3,64,1024)
    const float* Wih = (const float*)d_in[2];   // (3,3072,1024)
    const float* Whh = (const float*)d_in[3];   // (3,3072,1024)
    const float* bih = (const float*)d_in[4];   // (3,3072)
    const float* bhh = (const float*)d_in[5];   // (3,3072)

    char* ws = (char*)d_ws;
    _Float16* xh   = (_Float16*)(ws + 0);            //  67,108,864
    _Float16* xl   = (_Float16*)(ws + 67108864);     //  67,108,864
    _Float16* W0h  = (_Float16*)(ws + 134217728);    //  12,582,912
    _Float16* W0l  = (_Float16*)(ws + 146800640);    //  12,582,912
    _Float16* W12h = (_Float16*)(ws + 159383552);    //  16,777,216
    _Float16* W12l = (_Float16*)(ws + 176160768);    //  16,777,216
    float*    bsum = (float*)   (ws + 192937984);    //      36,864
    float*    h32  = (float*)   (ws + 192974848);    //   1,572,864 (2 slots)
    _Float16* hhb  = (_Float16*)(ws + 194547712);    //     786,432 (2 slots)
    _Float16* hlb  = (_Float16*)(ws + 195334144);    //     786,432 (2 slots)
    // total ~196.1 MB

    const int thr = 256;
    const int LW = 3072 * 1024;   // per-layer weight stride in inputs

    split_kernel4<<<4096, thr, 0, stream>>>((const float4*)x, (f16x4*)xh, (f16x4*)xl, 8388608);
    split_kernel4<<<3072, thr, 0, stream>>>((const float4*)Wih, (f16x4*)W0h, (f16x4*)W0l, 786432);
    split_kernel4<<<3072, thr, 0, stream>>>((const float4*)Whh,
                                            (f16x4*)(W0h + 3072 * 1024), (f16x4*)(W0l + 3072 * 1024), 786432);
    for (int l = 1; l <= 2; ++l) {
        size_t dst = (size_t)(l - 1) * 4096 * 1024;
        sumsplit_kernel4<<<2048, thr, 0, stream>>>((const float4*)(Wih + (size_t)l * LW),
                                                   (const float4*)(Whh + (size_t)l * LW),
                                                   (f16x4*)(W12h + dst), (f16x4*)(W12l + dst),
                                                   2048 * 1024 / 4);
        split_kernel4<<<1024, thr, 0, stream>>>((const float4*)(Wih + (size_t)l * LW + 2048 * 1024),
                                                (f16x4*)(W12h + dst + 2048 * 1024),
                                                (f16x4*)(W12l + dst + 2048 * 1024), 262144);
        split_kernel4<<<1024, thr, 0, stream>>>((const float4*)(Whh + (size_t)l * LW + 2048 * 1024),
                                                (f16x4*)(W12h + dst + 3072 * 1024),
                                                (f16x4*)(W12l + dst + 3072 * 1024), 262144);
    }
    bias_kernel<<<36, thr, 0, stream>>>(bih, bhh, bsum, 9216);
    hinit_kernel<<<192, thr, 0, stream>>>((const float4*)h0, (float4*)h32,
                                          (f16x4*)hhb, (f16x4*)hlb, LBH / 4);

    for (int t = 0; t < NSTEP; ++t) {
        int s0 = t & 1, s1 = (t + 1) & 1;
        float* h32d = (t == NSTEP - 1) ? (float*)d_out : h32 + s1 * LBH;
        gru_step<<<256, 256, 0, stream>>>(xh + (size_t)t * NB * HD, xl + (size_t)t * NB * HD,
                                          hhb + s0 * LBH, hlb + s0 * LBH, h32 + s0 * LBH,
                                          hhb + s1 * LBH, hlb + s1 * LBH, h32d,
                                          W0h, W0l, W12h, W12l, bsum);
    }
}